// Round 1
// 372.910 us; speedup vs baseline: 1.0189x; 1.0189x over previous
//
#include <hip/hip_runtime.h>
#include <math.h>

#define H 160
#define W 480
#define HW 76800
#define NPTS 120000
#define NUNIT 6

// ws layout (bytes):
//   winner0 @ 0        (76800*4)
//   winner1 @ 307200
//   winner2 @ 614400
//   t9      @ 921600   planar: 6 units x 9 taps x [HW] floats = 16,588,800 B
//   Weff0   @ 17510400 (64*12*4  = 3072)   layout [c][12]
//   Weff1   @ 17513472 (128*12*4 = 6144)   layout [c][12]
//   bconst  @ 17519616 (9*4)
//   sa      @ 0        (aliases winner0; winners dead after t9_kernel)
#define OFF_W1M 307200
#define OFF_W2M 614400
#define OFF_T9  921600
#define OFF_WE0 17510400
#define OFF_WE1 17513472
#define OFF_BC  17519616

__global__ __launch_bounds__(256) void scatter_winners(
    const int2* __restrict__ g0, const int2* __restrict__ g1, const int2* __restrict__ g2,
    int* __restrict__ w0, int* __restrict__ w1, int* __restrict__ w2) {
  int j = blockIdx.x * blockDim.x + threadIdx.x;
  if (j >= NPTS) return;
  int2 c;
  c = g0[j];
  if ((unsigned)c.x < W && (unsigned)c.y < H) atomicMax(&w0[c.y * W + c.x], j);
  c = g1[j];
  if ((unsigned)c.x < W && (unsigned)c.y < H) atomicMax(&w1[c.y * W + c.x], j);
  c = g2[j];
  if ((unsigned)c.x < W && (unsigned)c.y < H) atomicMax(&w2[c.y * W + c.x], j);
}

// Weff layouts are [in_channel][12] (stride 12 floats, 9 used) so the
// per-pixel kernel walks channels with wave-uniform addresses (s_load).
__global__ __launch_bounds__(256) void prep_weights(
    const float* __restrict__ rw0, const float* __restrict__ rw1,
    const float* __restrict__ rb0, const float* __restrict__ rb1,
    const float* __restrict__ sbw,
    float* __restrict__ Weff0, float* __restrict__ Weff1, float* __restrict__ bconst) {
  int t = blockIdx.x * blockDim.x + threadIdx.x;
  if (t < 576) {
    int jj = t / 64, k = t % 64;
    float s = 0.f;
    for (int c = 0; c < 256; ++c) s = fmaf(rw0[c * 64 + k], sbw[(256 + c) * 9 + jj], s);
    Weff0[k * 12 + jj] = s;
  } else if (t < 1728) {
    int tt = t - 576;
    int jj = tt / 128, k = tt % 128;
    float s = 0.f;
    for (int c = 0; c < 256; ++c) s = fmaf(rw1[c * 128 + k], sbw[(256 + c) * 9 + jj], s);
    Weff1[k * 12 + jj] = s;
  } else if (t < 1737) {
    int jj = t - 1728;
    float s = 0.f;
    for (int c = 0; c < 256; ++c) s = fmaf(rb0[c] + rb1[c], sbw[(256 + c) * 9 + jj], s);
    bconst[jj] = s;
  }
}

// Load the ENTIRE gather set into registers (constant-indexed array -> VGPRs)
// before any FMA: ~NF4 outstanding 16B loads per wave instead of ~6 at the
// old 28-VGPR allocation. Weight base is wave-uniform -> s_load.
template <int NF4, int WS>
__device__ __forceinline__ void gath(const float* __restrict__ row,
                                     const float* __restrict__ wbase,
                                     float acc[9]) {
  float4 v[NF4];
#pragma unroll
  for (int i = 0; i < NF4; ++i) v[i] = reinterpret_cast<const float4*>(row)[i];
#pragma unroll
  for (int i = 0; i < NF4; ++i) {
    const float* wc = wbase + i * 4 * WS;
#pragma unroll
    for (int j = 0; j < 9; ++j) {
      acc[j] = fmaf(v[i].x, wc[j], acc[j]);
      acc[j] = fmaf(v[i].y, wc[WS + j], acc[j]);
      acc[j] = fmaf(v[i].z, wc[2 * WS + j], acc[j]);
      acc[j] = fmaf(v[i].w, wc[3 * WS + j], acc[j]);
    }
  }
}

// Thread-per-pixel, uniform work unit per blockIdx.y (6 units, balanced):
//   unit 0: img c[0,128)   * seg      (coalesced stream)
//   unit 1: img c[128,256) * seg      (coalesced stream)
//   unit 2: vox L0 all 64   + L1 c[0,48)      (16+12 = 28 f4 gathers)
//   unit 3: vox L1 c[48,128)+ L2 c[0,32)      (20+8  = 28 f4 gathers)
//   unit 4: vox L2 c[32,144)                  (28 f4 gathers)
//   unit 5: vox L2 c[144,256)                 (28 f4 gathers)
// Output planar: t9[(u*9 + j)*HW + p]  -> coalesced stores AND coalesced
// reads in conv_sig.
__global__ __launch_bounds__(256, 3) void t9_kernel(
    const float* __restrict__ img, const float* __restrict__ seg,
    const float* __restrict__ vf0, const float* __restrict__ vf1,
    const float* __restrict__ vf2,
    const int* __restrict__ w0m, const int* __restrict__ w1m,
    const int* __restrict__ w2m,
    const float* __restrict__ We0, const float* __restrict__ We1,
    const float* __restrict__ sbw, float* __restrict__ t9) {
  int p = blockIdx.x * 256 + threadIdx.x;  // exact 76800
  int u = blockIdx.y;
  float acc[9];
#pragma unroll
  for (int j = 0; j < 9; ++j) acc[j] = 0.f;

  if (u < 2) {
    const int c0 = u * 128;
    float s = seg[HW + p];
    for (int cc = 0; cc < 128; cc += 16) {  // batch 16 coalesced loads, then FMA
      float v[16];
#pragma unroll
      for (int t = 0; t < 16; ++t) v[t] = img[(size_t)(c0 + cc + t) * HW + p];
#pragma unroll
      for (int t = 0; t < 16; ++t) {
        const float* wr = sbw + (c0 + cc + t) * 9;
#pragma unroll
        for (int j = 0; j < 9; ++j) acc[j] = fmaf(v[t], wr[j], acc[j]);
      }
    }
#pragma unroll
    for (int j = 0; j < 9; ++j) acc[j] *= s;
  } else if (u == 2) {
    int w0 = w0m[p];
    if (w0 >= 0) gath<16, 12>(vf0 + (size_t)w0 * 64, We0, acc);
    int w1 = w1m[p];
    if (w1 >= 0) gath<12, 12>(vf1 + (size_t)w1 * 128, We1, acc);
  } else if (u == 3) {
    int w1 = w1m[p];
    if (w1 >= 0) gath<20, 12>(vf1 + (size_t)w1 * 128 + 48, We1 + 48 * 12, acc);
    int w2 = w2m[p];
    if (w2 >= 0) gath<8, 9>(vf2 + (size_t)w2 * 256, sbw + 256 * 9, acc);
  } else if (u == 4) {
    int w2 = w2m[p];
    if (w2 >= 0) gath<28, 9>(vf2 + (size_t)w2 * 256 + 32, sbw + (256 + 32) * 9, acc);
  } else {
    int w2 = w2m[p];
    if (w2 >= 0) gath<28, 9>(vf2 + (size_t)w2 * 256 + 144, sbw + (256 + 144) * 9, acc);
  }

  float* dst = t9 + (size_t)u * 9 * HW + p;
#pragma unroll
  for (int j = 0; j < 9; ++j) dst[(size_t)j * HW] = acc[j];  // 9 coalesced stores
}

// attention = sigmoid(sb_b + sum over valid taps (bconst[j] + sum_units t9[u][j][q]))
// All 54 t9 reads are coalesced planar loads now.
__global__ __launch_bounds__(256) void conv_sig_kernel(
    const float* __restrict__ t9, const float* __restrict__ bconst,
    const float* __restrict__ sbb, const float* __restrict__ seg,
    float* __restrict__ sa) {
  int p = blockIdx.x * blockDim.x + threadIdx.x;  // exact 76800
  int y = p / W, x = p - y * W;
  float s = sbb[0];
#pragma unroll
  for (int dy = -1; dy <= 1; ++dy) {
#pragma unroll
    for (int dx = -1; dx <= 1; ++dx) {
      int yy = y + dy, xx = x + dx;
      if ((unsigned)yy < H && (unsigned)xx < W) {
        int j = (dy + 1) * 3 + (dx + 1);
        int q = yy * W + xx;
        float t = bconst[j];
#pragma unroll
        for (int u = 0; u < NUNIT; ++u) t += t9[(size_t)(u * 9 + j) * HW + q];
        s += t;
      }
    }
  }
  float att = 1.f / (1.f + expf(-s));
  sa[p] = att * seg[HW + p];
}

// out[c][p] = img[c][p] * sa[p]   (float4 over 19.66M elems)
__global__ __launch_bounds__(256) void final_mul_kernel(
    const float* __restrict__ img, const float* __restrict__ sa, float* __restrict__ out) {
  int i = blockIdx.x * blockDim.x + threadIdx.x;  // float4 index, exact 4915200
  int e = i * 4;
  int p = e % HW;  // 76800 % 4 == 0 so float4 stays within one channel row
  float4 v = *(const float4*)(img + e);
  float4 g = *(const float4*)(sa + p);
  float4 o = make_float4(v.x * g.x, v.y * g.y, v.z * g.z, v.w * g.w);
  *(float4*)(out + e) = o;
}

extern "C" void kernel_launch(void* const* d_in, const int* in_sizes, int n_in,
                              void* d_out, int out_size, void* d_ws, size_t ws_size,
                              hipStream_t stream) {
  const float* img = (const float*)d_in[0];
  const float* seg = (const float*)d_in[1];
  // setup_inputs() dict order interleaves voxel_feat{i}/img_grid{i}; detect defensively.
  int iV0 = 2, iG0 = 3, iV1 = 4, iG1 = 5, iV2 = 6, iG2 = 7;
  if (in_sizes[3] != 2 * NPTS) {  // grouped (reference-arg) order fallback
    iV0 = 2; iV1 = 3; iV2 = 4; iG0 = 5; iG1 = 6; iG2 = 7;
  }
  const float* vf0 = (const float*)d_in[iV0];
  const float* vf1 = (const float*)d_in[iV1];
  const float* vf2 = (const float*)d_in[iV2];
  const int2* g0 = (const int2*)d_in[iG0];
  const int2* g1 = (const int2*)d_in[iG1];
  const int2* g2 = (const int2*)d_in[iG2];
  const float* rw0 = (const float*)d_in[8];
  const float* rb0 = (const float*)d_in[9];
  const float* rw1 = (const float*)d_in[10];
  const float* rb1 = (const float*)d_in[11];
  const float* sbw = (const float*)d_in[12];
  const float* sbb = (const float*)d_in[13];

  char* ws = (char*)d_ws;
  int* w0m = (int*)(ws + 0);
  int* w1m = (int*)(ws + OFF_W1M);
  int* w2m = (int*)(ws + OFF_W2M);
  float* t9 = (float*)(ws + OFF_T9);
  float* Weff0 = (float*)(ws + OFF_WE0);
  float* Weff1 = (float*)(ws + OFF_WE1);
  float* bconst = (float*)(ws + OFF_BC);
  float* sa = (float*)(ws + 0);  // aliases winner maps (dead after t9_kernel)

  float* out = (float*)d_out;

  hipMemsetAsync(w0m, 0xFF, 3 * 307200, stream);  // winners = -1
  prep_weights<<<7, 256, 0, stream>>>(rw0, rw1, rb0, rb1, sbw, Weff0, Weff1, bconst);
  scatter_winners<<<(NPTS + 255) / 256, 256, 0, stream>>>(g0, g1, g2, w0m, w1m, w2m);
  dim3 tg(HW / 256, NUNIT);
  t9_kernel<<<tg, 256, 0, stream>>>(img, seg, vf0, vf1, vf2, w0m, w1m, w2m,
                                    Weff0, Weff1, sbw, t9);
  conv_sig_kernel<<<HW / 256, 256, 0, stream>>>(t9, bconst, sbb, seg, sa);
  final_mul_kernel<<<(out_size / 4) / 256, 256, 0, stream>>>(img, sa, out);
}

// Round 2
// 368.625 us; speedup vs baseline: 1.0307x; 1.0116x over previous
//
#include <hip/hip_runtime.h>
#include <math.h>

#define H 160
#define W 480
#define HW 76800
#define NPTS 120000
#define NUNIT 6

// ws layout (bytes):
//   winner0 @ 0        (76800*4)
//   winner1 @ 307200
//   winner2 @ 614400
//   t9      @ 921600   planar: 6 units x 9 taps x [HW] floats = 16,588,800 B
//   Weff0   @ 17510400 (64*12*4  = 3072)   layout [c][12]
//   Weff1   @ 17513472 (128*12*4 = 6144)   layout [c][12]
//   bconst  @ 17519616 (9*4)
//   sa      @ 0        (aliases winner0; winners dead after t9_kernel)
#define OFF_W1M 307200
#define OFF_W2M 614400
#define OFF_T9  921600
#define OFF_WE0 17510400
#define OFF_WE1 17513472
#define OFF_BC  17519616

// Merged: blocks [0,7) do weight-folding, blocks [7,476) do winner scatter.
// Saves one dispatch; the two jobs touch disjoint data.
__global__ __launch_bounds__(256) void prep_and_scatter(
    const float* __restrict__ rw0, const float* __restrict__ rw1,
    const float* __restrict__ rb0, const float* __restrict__ rb1,
    const float* __restrict__ sbw,
    float* __restrict__ Weff0, float* __restrict__ Weff1, float* __restrict__ bconst,
    const int2* __restrict__ g0, const int2* __restrict__ g1, const int2* __restrict__ g2,
    int* __restrict__ w0, int* __restrict__ w1, int* __restrict__ w2) {
  if (blockIdx.x < 7) {
    int t = blockIdx.x * 256 + threadIdx.x;
    if (t < 576) {
      int jj = t / 64, k = t % 64;
      float s = 0.f;
      for (int c = 0; c < 256; ++c) s = fmaf(rw0[c * 64 + k], sbw[(256 + c) * 9 + jj], s);
      Weff0[k * 12 + jj] = s;
    } else if (t < 1728) {
      int tt = t - 576;
      int jj = tt / 128, k = tt % 128;
      float s = 0.f;
      for (int c = 0; c < 256; ++c) s = fmaf(rw1[c * 128 + k], sbw[(256 + c) * 9 + jj], s);
      Weff1[k * 12 + jj] = s;
    } else if (t < 1737) {
      int jj = t - 1728;
      float s = 0.f;
      for (int c = 0; c < 256; ++c) s = fmaf(rb0[c] + rb1[c], sbw[(256 + c) * 9 + jj], s);
      bconst[jj] = s;
    }
  } else {
    int j = (blockIdx.x - 7) * 256 + threadIdx.x;
    if (j >= NPTS) return;
    int2 c;
    c = g0[j];
    if ((unsigned)c.x < W && (unsigned)c.y < H) atomicMax(&w0[c.y * W + c.x], j);
    c = g1[j];
    if ((unsigned)c.x < W && (unsigned)c.y < H) atomicMax(&w1[c.y * W + c.x], j);
    c = g2[j];
    if ((unsigned)c.x < W && (unsigned)c.y < H) atomicMax(&w2[c.y * W + c.x], j);
  }
}

template <int NF4>
__device__ __forceinline__ void ld_batch(const float4* __restrict__ r, float4* v) {
#pragma unroll
  for (int i = 0; i < NF4; ++i) v[i] = r[i];
}

// Weff layouts are [c][WS] with WS=12 (Weff0/1) or 9 (direct sbw); base is
// wave-uniform -> s_load.
template <int NF4, int WS>
__device__ __forceinline__ void fma_batch(const float4* v, const float* __restrict__ wbase,
                                          float acc[9]) {
#pragma unroll
  for (int i = 0; i < NF4; ++i) {
    const float* wc = wbase + i * 4 * WS;
#pragma unroll
    for (int j = 0; j < 9; ++j) {
      acc[j] = fmaf(v[i].x, wc[j], acc[j]);
      acc[j] = fmaf(v[i].y, wc[WS + j], acc[j]);
      acc[j] = fmaf(v[i].z, wc[2 * WS + j], acc[j]);
      acc[j] = fmaf(v[i].w, wc[3 * WS + j], acc[j]);
    }
  }
}

// Thread-per-pixel, uniform work unit per blockIdx.y (6 units, balanced):
//   unit 0: img c[0,128)   * seg      (coalesced stream)
//   unit 1: img c[128,256) * seg      (coalesced stream)
//   unit 2: vox L0 all 64   + L1 c[0,48)      (16+12 = 28 f4 gathers)
//   unit 3: vox L1 c[48,128)+ L2 c[0,32)      (20+8  = 28 f4 gathers)
//   unit 4: vox L2 c[32,144)                  (28 f4 gathers)
//   unit 5: vox L2 c[144,256)                 (28 f4 gathers)
// KEY CHANGE vs round 1: the full gather batch is issued BEFORE any FMA and
// pinned with sched_barrier(0) so the scheduler cannot sink the loads
// (round-1 post-mortem: VGPR stayed 36 -> only ~6 loads in flight). Empty
// cells load row 0 (L2-hot) so the batch issue is branch-free; FMAs stay
// guarded by the winner test.
__global__ __launch_bounds__(256, 3) void t9_kernel(
    const float* __restrict__ img, const float* __restrict__ seg,
    const float* __restrict__ vf0, const float* __restrict__ vf1,
    const float* __restrict__ vf2,
    const int* __restrict__ w0m, const int* __restrict__ w1m,
    const int* __restrict__ w2m,
    const float* __restrict__ We0, const float* __restrict__ We1,
    const float* __restrict__ sbw, float* __restrict__ t9) {
  int p = blockIdx.x * 256 + threadIdx.x;  // exact 76800
  int u = blockIdx.y;
  float acc[9];
#pragma unroll
  for (int j = 0; j < 9; ++j) acc[j] = 0.f;

  if (u < 2) {
    const int c0 = u * 128;
    float s = seg[HW + p];
    for (int cc = 0; cc < 128; cc += 16) {
      float v[16];
#pragma unroll
      for (int t = 0; t < 16; ++t) v[t] = img[(size_t)(c0 + cc + t) * HW + p];
      __builtin_amdgcn_sched_barrier(0);
#pragma unroll
      for (int t = 0; t < 16; ++t) {
        const float* wr = sbw + (c0 + cc + t) * 9;
#pragma unroll
        for (int j = 0; j < 9; ++j) acc[j] = fmaf(v[t], wr[j], acc[j]);
      }
    }
#pragma unroll
    for (int j = 0; j < 9; ++j) acc[j] *= s;
  } else if (u == 2) {
    int w0 = w0m[p], w1 = w1m[p];
    const float4* r0 = (const float4*)(vf0 + (size_t)(w0 < 0 ? 0 : w0) * 64);
    const float4* r1 = (const float4*)(vf1 + (size_t)(w1 < 0 ? 0 : w1) * 128);
    float4 v0[16], v1[12];
    ld_batch<16>(r0, v0);
    ld_batch<12>(r1, v1);
    __builtin_amdgcn_sched_barrier(0);
    if (w0 >= 0) fma_batch<16, 12>(v0, We0, acc);
    if (w1 >= 0) fma_batch<12, 12>(v1, We1, acc);
  } else if (u == 3) {
    int w1 = w1m[p], w2 = w2m[p];
    const float4* r1 = (const float4*)(vf1 + (size_t)(w1 < 0 ? 0 : w1) * 128 + 48);
    const float4* r2 = (const float4*)(vf2 + (size_t)(w2 < 0 ? 0 : w2) * 256);
    float4 v1[20], v2[8];
    ld_batch<20>(r1, v1);
    ld_batch<8>(r2, v2);
    __builtin_amdgcn_sched_barrier(0);
    if (w1 >= 0) fma_batch<20, 12>(v1, We1 + 48 * 12, acc);
    if (w2 >= 0) fma_batch<8, 9>(v2, sbw + 256 * 9, acc);
  } else {
    int cbase = (u == 4) ? 32 : 144;
    int w2 = w2m[p];
    const float4* r2 = (const float4*)(vf2 + (size_t)(w2 < 0 ? 0 : w2) * 256 + cbase);
    float4 v2[28];
    ld_batch<28>(r2, v2);
    __builtin_amdgcn_sched_barrier(0);
    if (w2 >= 0) fma_batch<28, 9>(v2, sbw + (256 + cbase) * 9, acc);
  }

  float* dst = t9 + (size_t)u * 9 * HW + p;
#pragma unroll
  for (int j = 0; j < 9; ++j) dst[(size_t)j * HW] = acc[j];  // 9 coalesced stores
}

// attention = sigmoid(sb_b + sum over valid taps (bconst[j] + sum_units t9[u][j][q]))
// All 54 t9 reads are coalesced planar loads.
__global__ __launch_bounds__(256) void conv_sig_kernel(
    const float* __restrict__ t9, const float* __restrict__ bconst,
    const float* __restrict__ sbb, const float* __restrict__ seg,
    float* __restrict__ sa) {
  int p = blockIdx.x * blockDim.x + threadIdx.x;  // exact 76800
  int y = p / W, x = p - y * W;
  float s = sbb[0];
#pragma unroll
  for (int dy = -1; dy <= 1; ++dy) {
#pragma unroll
    for (int dx = -1; dx <= 1; ++dx) {
      int yy = y + dy, xx = x + dx;
      if ((unsigned)yy < H && (unsigned)xx < W) {
        int j = (dy + 1) * 3 + (dx + 1);
        int q = yy * W + xx;
        float t = bconst[j];
#pragma unroll
        for (int u = 0; u < NUNIT; ++u) t += t9[(size_t)(u * 9 + j) * HW + q];
        s += t;
      }
    }
  }
  float att = 1.f / (1.f + expf(-s));
  sa[p] = att * seg[HW + p];
}

// out[c][p] = img[c][p] * sa[p]   (float4 over 19.66M elems)
__global__ __launch_bounds__(256) void final_mul_kernel(
    const float* __restrict__ img, const float* __restrict__ sa, float* __restrict__ out) {
  int i = blockIdx.x * blockDim.x + threadIdx.x;  // float4 index, exact 4915200
  int e = i * 4;
  int p = e % HW;  // 76800 % 4 == 0 so float4 stays within one channel row
  float4 v = *(const float4*)(img + e);
  float4 g = *(const float4*)(sa + p);
  float4 o = make_float4(v.x * g.x, v.y * g.y, v.z * g.z, v.w * g.w);
  *(float4*)(out + e) = o;
}

extern "C" void kernel_launch(void* const* d_in, const int* in_sizes, int n_in,
                              void* d_out, int out_size, void* d_ws, size_t ws_size,
                              hipStream_t stream) {
  const float* img = (const float*)d_in[0];
  const float* seg = (const float*)d_in[1];
  // setup_inputs() dict order interleaves voxel_feat{i}/img_grid{i}; detect defensively.
  int iV0 = 2, iG0 = 3, iV1 = 4, iG1 = 5, iV2 = 6, iG2 = 7;
  if (in_sizes[3] != 2 * NPTS) {  // grouped (reference-arg) order fallback
    iV0 = 2; iV1 = 3; iV2 = 4; iG0 = 5; iG1 = 6; iG2 = 7;
  }
  const float* vf0 = (const float*)d_in[iV0];
  const float* vf1 = (const float*)d_in[iV1];
  const float* vf2 = (const float*)d_in[iV2];
  const int2* g0 = (const int2*)d_in[iG0];
  const int2* g1 = (const int2*)d_in[iG1];
  const int2* g2 = (const int2*)d_in[iG2];
  const float* rw0 = (const float*)d_in[8];
  const float* rb0 = (const float*)d_in[9];
  const float* rw1 = (const float*)d_in[10];
  const float* rb1 = (const float*)d_in[11];
  const float* sbw = (const float*)d_in[12];
  const float* sbb = (const float*)d_in[13];

  char* ws = (char*)d_ws;
  int* w0m = (int*)(ws + 0);
  int* w1m = (int*)(ws + OFF_W1M);
  int* w2m = (int*)(ws + OFF_W2M);
  float* t9 = (float*)(ws + OFF_T9);
  float* Weff0 = (float*)(ws + OFF_WE0);
  float* Weff1 = (float*)(ws + OFF_WE1);
  float* bconst = (float*)(ws + OFF_BC);
  float* sa = (float*)(ws + 0);  // aliases winner maps (dead after t9_kernel)

  float* out = (float*)d_out;

  hipMemsetAsync(w0m, 0xFF, 3 * 307200, stream);  // winners = -1
  prep_and_scatter<<<7 + (NPTS + 255) / 256, 256, 0, stream>>>(
      rw0, rw1, rb0, rb1, sbw, Weff0, Weff1, bconst, g0, g1, g2, w0m, w1m, w2m);
  dim3 tg(HW / 256, NUNIT);
  t9_kernel<<<tg, 256, 0, stream>>>(img, seg, vf0, vf1, vf2, w0m, w1m, w2m,
                                    Weff0, Weff1, sbw, t9);
  conv_sig_kernel<<<HW / 256, 256, 0, stream>>>(t9, bconst, sbb, seg, sa);
  final_mul_kernel<<<(out_size / 4) / 256, 256, 0, stream>>>(img, sa, out);
}